// Round 2
// baseline (3557.621 us; speedup 1.0000x reference)
//
#include <hip/hip_runtime.h>
#include <math.h>

#define NT_NODES 30000
#define NE_EDGES 200000
#define NTY 3
#define NRL 4
#define NLY 2
#define NH 8
#define HD 16
#define FDIM 128

// ---------------------------------------------------------------- GEMM ------
struct GemmTask {
  const float* A; const float* W; const float* bias; float* C;
  const float* oldh; const float* skipp;
};
struct GemmBatch { GemmTask t[3]; };

__device__ __forceinline__ float gelu_f(float x) {
  return 0.5f * x * (1.f + erff(x * 0.7071067811865475f));
}

// C[M,128] = epi(preA(A)[M,128] @ W[128,128] + bias)
template<int GELU_A, int EPI_SKIP, int RELU>
__global__ __launch_bounds__(256) void gemm_f32(GemmBatch gb, int M) {
  const GemmTask tk = gb.t[blockIdx.z];
  const int tid = threadIdx.x;
  const int tx2 = tid & 15;    // col group of 8
  const int ty2 = tid >> 4;    // row group of 4
  const int row0 = blockIdx.x * 64;

  __shared__ float AsT[32][64];   // transposed A chunk [k][row]
  __shared__ float Bs[32][128];   // B chunk [k][col]

  float acc[4][8];
  #pragma unroll
  for (int i = 0; i < 4; i++)
    #pragma unroll
    for (int j = 0; j < 8; j++) acc[i][j] = 0.f;

  for (int k0 = 0; k0 < FDIM; k0 += 32) {
    #pragma unroll
    for (int i = 0; i < 2; i++) {
      int slot = tid + 256 * i;         // 0..511
      int r = slot >> 3, f4 = slot & 7;
      int grow = row0 + r;
      float4 v = make_float4(0.f, 0.f, 0.f, 0.f);
      if (grow < M) v = *(const float4*)(tk.A + (size_t)grow * FDIM + k0 + f4 * 4);
      if (GELU_A) { v.x = gelu_f(v.x); v.y = gelu_f(v.y); v.z = gelu_f(v.z); v.w = gelu_f(v.w); }
      AsT[f4 * 4 + 0][r] = v.x;
      AsT[f4 * 4 + 1][r] = v.y;
      AsT[f4 * 4 + 2][r] = v.z;
      AsT[f4 * 4 + 3][r] = v.w;
    }
    #pragma unroll
    for (int i = 0; i < 4; i++) {
      int slot = tid + 256 * i;         // 0..1023
      int r = slot >> 5, f4 = slot & 31;
      float4 v = *(const float4*)(tk.W + (size_t)(k0 + r) * FDIM + f4 * 4);
      *(float4*)(&Bs[r][f4 * 4]) = v;
    }
    __syncthreads();
    #pragma unroll
    for (int kk = 0; kk < 32; kk++) {
      float4 a4 = *(const float4*)(&AsT[kk][ty2 * 4]);
      float4 b0 = *(const float4*)(&Bs[kk][tx2 * 8]);
      float4 b1 = *(const float4*)(&Bs[kk][tx2 * 8 + 4]);
      const float av[4] = {a4.x, a4.y, a4.z, a4.w};
      #pragma unroll
      for (int i = 0; i < 4; i++) {
        acc[i][0] += av[i] * b0.x; acc[i][1] += av[i] * b0.y;
        acc[i][2] += av[i] * b0.z; acc[i][3] += av[i] * b0.w;
        acc[i][4] += av[i] * b1.x; acc[i][5] += av[i] * b1.y;
        acc[i][6] += av[i] * b1.z; acc[i][7] += av[i] * b1.w;
      }
    }
    __syncthreads();
  }

  float4 bias0 = *(const float4*)(tk.bias + tx2 * 8);
  float4 bias1 = *(const float4*)(tk.bias + tx2 * 8 + 4);
  float a_s = 0.f;
  if (EPI_SKIP) a_s = 1.f / (1.f + expf(-tk.skipp[0]));

  #pragma unroll
  for (int i = 0; i < 4; i++) {
    int grow = row0 + ty2 * 4 + i;
    if (grow >= M) continue;
    float o[8];
    o[0] = acc[i][0] + bias0.x; o[1] = acc[i][1] + bias0.y;
    o[2] = acc[i][2] + bias0.z; o[3] = acc[i][3] + bias0.w;
    o[4] = acc[i][4] + bias1.x; o[5] = acc[i][5] + bias1.y;
    o[6] = acc[i][6] + bias1.z; o[7] = acc[i][7] + bias1.w;
    if (RELU) {
      #pragma unroll
      for (int j = 0; j < 8; j++) o[j] = fmaxf(o[j], 0.f);
    }
    if (EPI_SKIP) {
      const float* hp = tk.oldh + (size_t)grow * FDIM + tx2 * 8;
      float4 h0 = *(const float4*)(hp);
      float4 h1 = *(const float4*)(hp + 4);
      float b_s = 1.f - a_s;
      o[0] = a_s * o[0] + b_s * h0.x; o[1] = a_s * o[1] + b_s * h0.y;
      o[2] = a_s * o[2] + b_s * h0.z; o[3] = a_s * o[3] + b_s * h0.w;
      o[4] = a_s * o[4] + b_s * h1.x; o[5] = a_s * o[5] + b_s * h1.y;
      o[6] = a_s * o[6] + b_s * h1.z; o[7] = a_s * o[7] + b_s * h1.w;
    }
    float* cp = tk.C + (size_t)grow * FDIM + tx2 * 8;
    *(float4*)cp = make_float4(o[0], o[1], o[2], o[3]);
    *(float4*)(cp + 4) = make_float4(o[4], o[5], o[6], o[7]);
  }
}

// ------------------------------------------------------- fused rel weights --
// Wf[c, h*16+e] = sum_d W[c, h*16+d] * rel[h, d, e];  bf likewise from bias.
struct FuseBatch { const float* w[8]; const float* b[8]; const float* rel[8]; };

__global__ __launch_bounds__(256) void fuse_w(FuseBatch fb, float* wf, float* bf) {
  const int bx = blockIdx.x;
  const float* w = fb.w[bx];
  const float* bb = fb.b[bx];
  const float* rel = fb.rel[bx];
  float* wo = wf + (size_t)bx * FDIM * FDIM;
  float* bo = bf + (size_t)bx * FDIM;
  __shared__ float rl[NH * HD * HD];
  for (int i = threadIdx.x; i < NH * HD * HD; i += 256) rl[i] = rel[i];
  __syncthreads();
  for (int idx = threadIdx.x; idx < FDIM * FDIM; idx += 256) {
    int c = idx >> 7, he = idx & 127, h = he >> 4, e2 = he & 15;
    float s = 0.f;
    #pragma unroll
    for (int d2 = 0; d2 < HD; d2++)
      s += w[c * FDIM + h * HD + d2] * rl[h * HD * HD + d2 * HD + e2];
    wo[idx] = s;
  }
  if (threadIdx.x < FDIM) {
    int he = threadIdx.x, h = he >> 4, e2 = he & 15;
    float s = 0.f;
    #pragma unroll
    for (int d2 = 0; d2 < HD; d2++)
      s += bb[h * HD + d2] * rl[h * HD * HD + d2 * HD + e2];
    bo[he] = s;
  }
}

// ------------------------------------------------------------ edge kernels --
__global__ __launch_bounds__(256) void edge_logits(
    const int* __restrict__ src, const int* __restrict__ dst,
    const float* __restrict__ q_d, const float* __restrict__ krel,
    const float* __restrict__ prel, float* __restrict__ ebuf,
    float* __restrict__ sum) {
  int idx = blockIdx.x * 256 + threadIdx.x;
  if (idx >= NE_EDGES * NH) return;
  int e = idx >> 3, h = idx & 7;
  int s = src[e], d = dst[e];
  const float4* qp = (const float4*)(q_d + (size_t)d * FDIM + h * HD);
  const float4* kp = (const float4*)(krel + (size_t)s * FDIM + h * HD);
  float dot = 0.f;
  #pragma unroll
  for (int i = 0; i < 4; i++) {
    float4 a = qp[i], b = kp[i];
    dot += a.x * b.x + a.y * b.y + a.z * b.z + a.w * b.w;
  }
  // inv_sqrt_d = 1/sqrt(16) = 0.25 exactly; max-subtraction dropped (logits tiny)
  float v = expf(dot * prel[h] * 0.25f);
  ebuf[idx] = v;
  atomicAdd(sum + (size_t)d * NH + h, v);
}

__global__ __launch_bounds__(256) void edge_msg(
    const int* __restrict__ src, const int* __restrict__ dst,
    const float* __restrict__ vrel, const float* __restrict__ ebuf,
    const float* __restrict__ sum, float* __restrict__ agg) {
  int idx = blockIdx.x * 256 + threadIdx.x;
  if (idx >= NE_EDGES * 32) return;
  int e = idx >> 5, c4 = idx & 31, h = c4 >> 2;
  int s = src[e], d = dst[e];
  float alpha = ebuf[(size_t)e * NH + h] / (sum[(size_t)d * NH + h] + 1e-16f);
  float4 v = ((const float4*)(vrel + (size_t)s * FDIM))[c4];
  float* ap = agg + (size_t)d * FDIM + c4 * 4;
  atomicAdd(ap + 0, v.x * alpha);
  atomicAdd(ap + 1, v.y * alpha);
  atomicAdd(ap + 2, v.z * alpha);
  atomicAdd(ap + 3, v.w * alpha);
}

// ---------------------------------------------------------------- scatter ---
__global__ __launch_bounds__(256) void scatter_out(const float* h0, const float* h1,
                                                   const float* h2, const int* ntype,
                                                   float* out, int NN) {
  int idx = blockIdx.x * 256 + threadIdx.x;
  if (idx >= NN * 32) return;
  int i = idx >> 5, c4 = idx & 31;
  int t = ntype[i];
  const float* hp = (t == 0) ? h0 : ((t == 1) ? h1 : h2);
  int local = i - t * NT_NODES;   // node_type_argmax is contiguous blocks per type
  ((float4*)out)[idx] = ((const float4*)hp)[(size_t)local * 32 + c4];
}

// ------------------------------------------------------------------- host ---
static const int ESRC[NRL] = {0, 0, 1, 0};
static const int EDST[NRL] = {0, 1, 0, 2};

extern "C" void kernel_launch(void* const* d_in, const int* in_sizes, int n_in,
                              void* d_out, int out_size, void* d_ws, size_t ws_size,
                              hipStream_t stream) {
  const float* x[3] = {(const float*)d_in[0], (const float*)d_in[1], (const float*)d_in[2]};
  const float* lin_w = (const float*)d_in[4];
  const float* lin_b = (const float*)d_in[5];
  const float* k_w   = (const float*)d_in[6];
  const float* k_b   = (const float*)d_in[7];
  const float* q_w   = (const float*)d_in[8];
  const float* q_b   = (const float*)d_in[9];
  const float* v_w   = (const float*)d_in[10];
  const float* v_b   = (const float*)d_in[11];
  const float* a_w   = (const float*)d_in[12];
  const float* a_b   = (const float*)d_in[13];
  const float* skip  = (const float*)d_in[14];
  const float* a_rel = (const float*)d_in[15];
  const float* m_rel = (const float*)d_in[16];
  const float* p_rel = (const float*)d_in[17];
  const int* edge_index = (const int*)d_in[18];
  const int* ntype   = (const int*)d_in[19];
  float* out = (float*)d_out;

  const size_t NF = (size_t)NT_NODES * FDIM;   // 3.84M floats per [N,128]
  // Slim workspace layout (~177 MB total; relations processed sequentially):
  float* p = (float*)d_ws;
  auto alloc = [&](size_t n) { float* r = p; p += n; return r; };
  float* bufA = alloc(3 * NF);                    // h (ping)
  float* bufB = alloc(3 * NF);                    // q-buffer / h (pong)
  float* agg  = alloc(3 * NF);                    // edge aggregation
  float* krel = alloc(NF);                        // per-relation K'
  float* vrel = alloc(NF);                        // per-relation V'
  float* sums = alloc((size_t)NT_NODES * NH);     // per-relation softmax denom
  float* ebuf = alloc((size_t)NE_EDGES * NH);     // per-relation exp(logit)
  float* wf   = alloc(8 * (size_t)FDIM * FDIM);   // fused K'/V' weights (8/layer)
  float* bf   = alloc(8 * (size_t)FDIM);

  const int gemm_gx = (NT_NODES + 63) / 64;   // 469

  // input projection: hs[t] = relu(x_t @ lin_w[t] + lin_b[t])
  {
    GemmBatch gb{};
    for (int t = 0; t < 3; t++) {
      gb.t[t].A = x[t];
      gb.t[t].W = lin_w + (size_t)t * FDIM * FDIM;
      gb.t[t].bias = lin_b + (size_t)t * FDIM;
      gb.t[t].C = bufA + (size_t)t * NF;
      gb.t[t].oldh = nullptr; gb.t[t].skipp = nullptr;
    }
    gemm_f32<0, 0, 1><<<dim3(gemm_gx, 1, 3), 256, 0, stream>>>(gb, NT_NODES);
  }

  float* cur = bufA;   // current h
  float* alt = bufB;   // q-buffer, then next h
  for (int l = 0; l < NLY; l++) {
    // fused K/V relation weights (8 tiny problems in one launch)
    {
      FuseBatch fb{};
      for (int r = 0; r < NRL; r++) {
        int s = ESRC[r];
        fb.w[2 * r]     = k_w + (size_t)(l * NTY + s) * FDIM * FDIM;
        fb.b[2 * r]     = k_b + (size_t)(l * NTY + s) * FDIM;
        fb.rel[2 * r]   = a_rel + (size_t)(l * NRL + r) * NH * HD * HD;
        fb.w[2 * r + 1]   = v_w + (size_t)(l * NTY + s) * FDIM * FDIM;
        fb.b[2 * r + 1]   = v_b + (size_t)(l * NTY + s) * FDIM;
        fb.rel[2 * r + 1] = m_rel + (size_t)(l * NRL + r) * NH * HD * HD;
      }
      fuse_w<<<dim3(8), 256, 0, stream>>>(fb, wf, bf);
    }
    hipMemsetAsync(agg, 0, 3 * NF * sizeof(float), stream);

    // q projections for all 3 types (into alt)
    {
      GemmBatch gb{};
      for (int t = 0; t < 3; t++) {
        gb.t[t].A = cur + (size_t)t * NF;
        gb.t[t].W = q_w + (size_t)(l * NTY + t) * FDIM * FDIM;
        gb.t[t].bias = q_b + (size_t)(l * NTY + t) * FDIM;
        gb.t[t].C = alt + (size_t)t * NF;
        gb.t[t].oldh = nullptr; gb.t[t].skipp = nullptr;
      }
      gemm_f32<0, 0, 0><<<dim3(gemm_gx, 1, 3), 256, 0, stream>>>(gb, NT_NODES);
    }

    // relations, sequential (krel/vrel/sums/ebuf reused)
    for (int r = 0; r < NRL; r++) {
      int s = ESRC[r], d = EDST[r];
      {
        GemmBatch gb{};
        gb.t[0].A = cur + (size_t)s * NF;
        gb.t[0].W = wf + (size_t)(2 * r) * FDIM * FDIM;
        gb.t[0].bias = bf + (size_t)(2 * r) * FDIM;
        gb.t[0].C = krel;
        gb.t[0].oldh = nullptr; gb.t[0].skipp = nullptr;
        gb.t[1].A = cur + (size_t)s * NF;
        gb.t[1].W = wf + (size_t)(2 * r + 1) * FDIM * FDIM;
        gb.t[1].bias = bf + (size_t)(2 * r + 1) * FDIM;
        gb.t[1].C = vrel;
        gb.t[1].oldh = nullptr; gb.t[1].skipp = nullptr;
        gemm_f32<0, 0, 0><<<dim3(gemm_gx, 1, 2), 256, 0, stream>>>(gb, NT_NODES);
      }
      hipMemsetAsync(sums, 0, (size_t)NT_NODES * NH * sizeof(float), stream);
      const int* srcp = edge_index + (size_t)(r * 2 + 0) * NE_EDGES;
      const int* dstp = edge_index + (size_t)(r * 2 + 1) * NE_EDGES;
      edge_logits<<<dim3((NE_EDGES * NH + 255) / 256), 256, 0, stream>>>(
          srcp, dstp, alt + (size_t)d * NF, krel,
          p_rel + (size_t)(l * NRL + r) * NH, ebuf, sums);
      edge_msg<<<dim3((NE_EDGES * 32 + 255) / 256), 256, 0, stream>>>(
          srcp, dstp, vrel, ebuf, sums, agg + (size_t)d * NF);
    }

    // out: hs_new[t] = a_s*(gelu(agg[t]) @ a_w + a_b) + (1-a_s)*hs[t]
    // writes over the q-buffer (q is dead now)
    {
      GemmBatch gb{};
      for (int t = 0; t < 3; t++) {
        gb.t[t].A = agg + (size_t)t * NF;
        gb.t[t].W = a_w + (size_t)(l * NTY + t) * FDIM * FDIM;
        gb.t[t].bias = a_b + (size_t)(l * NTY + t) * FDIM;
        gb.t[t].C = alt + (size_t)t * NF;
        gb.t[t].oldh = cur + (size_t)t * NF;
        gb.t[t].skipp = skip + (size_t)(l * NTY + t);
      }
      gemm_f32<1, 1, 0><<<dim3(gemm_gx, 1, 3), 256, 0, stream>>>(gb, NT_NODES);
    }
    float* tmp = cur; cur = alt; alt = tmp;
  }

  // scatter per-type rows back to global node order
  const int NN = 3 * NT_NODES;
  scatter_out<<<dim3((NN * 32 + 255) / 256), 256, 0, stream>>>(
      cur, cur + NF, cur + 2 * NF, ntype, out, NN);
}

// Round 3
// 1089.778 us; speedup vs baseline: 3.2645x; 3.2645x over previous
//
#include <hip/hip_runtime.h>
#include <math.h>

#define NT_NODES 30000
#define NE_EDGES 200000
#define NTY 3
#define NRL 4
#define NLY 2
#define NH 8
#define HD 16
#define FDIM 128

// ---------------------------------------------------------------- GEMM ------
struct GemmTask {
  const float* A; const float* W; const float* bias; float* C;
  const float* oldh; const float* skipp;
};
struct GemmBatch { GemmTask t[3]; };

__device__ __forceinline__ float gelu_f(float x) {
  return 0.5f * x * (1.f + erff(x * 0.7071067811865475f));
}

// C[M,128] = epi(preA(A)[M,128] @ W[128,128] + bias)
template<int GELU_A, int EPI_SKIP, int RELU>
__global__ __launch_bounds__(256) void gemm_f32(GemmBatch gb, int M) {
  const GemmTask tk = gb.t[blockIdx.z];
  const int tid = threadIdx.x;
  const int tx2 = tid & 15;    // col group of 8
  const int ty2 = tid >> 4;    // row group of 4
  const int row0 = blockIdx.x * 64;

  __shared__ float AsT[32][64];   // transposed A chunk [k][row]
  __shared__ float Bs[32][128];   // B chunk [k][col]

  float acc[4][8];
  #pragma unroll
  for (int i = 0; i < 4; i++)
    #pragma unroll
    for (int j = 0; j < 8; j++) acc[i][j] = 0.f;

  for (int k0 = 0; k0 < FDIM; k0 += 32) {
    #pragma unroll
    for (int i = 0; i < 2; i++) {
      int slot = tid + 256 * i;         // 0..511
      int r = slot >> 3, f4 = slot & 7;
      int grow = row0 + r;
      float4 v = make_float4(0.f, 0.f, 0.f, 0.f);
      if (grow < M) v = *(const float4*)(tk.A + (size_t)grow * FDIM + k0 + f4 * 4);
      if (GELU_A) { v.x = gelu_f(v.x); v.y = gelu_f(v.y); v.z = gelu_f(v.z); v.w = gelu_f(v.w); }
      AsT[f4 * 4 + 0][r] = v.x;
      AsT[f4 * 4 + 1][r] = v.y;
      AsT[f4 * 4 + 2][r] = v.z;
      AsT[f4 * 4 + 3][r] = v.w;
    }
    #pragma unroll
    for (int i = 0; i < 4; i++) {
      int slot = tid + 256 * i;         // 0..1023
      int r = slot >> 5, f4 = slot & 31;
      float4 v = *(const float4*)(tk.W + (size_t)(k0 + r) * FDIM + f4 * 4);
      *(float4*)(&Bs[r][f4 * 4]) = v;
    }
    __syncthreads();
    #pragma unroll
    for (int kk = 0; kk < 32; kk++) {
      float4 a4 = *(const float4*)(&AsT[kk][ty2 * 4]);
      float4 b0 = *(const float4*)(&Bs[kk][tx2 * 8]);
      float4 b1 = *(const float4*)(&Bs[kk][tx2 * 8 + 4]);
      const float av[4] = {a4.x, a4.y, a4.z, a4.w};
      #pragma unroll
      for (int i = 0; i < 4; i++) {
        acc[i][0] += av[i] * b0.x; acc[i][1] += av[i] * b0.y;
        acc[i][2] += av[i] * b0.z; acc[i][3] += av[i] * b0.w;
        acc[i][4] += av[i] * b1.x; acc[i][5] += av[i] * b1.y;
        acc[i][6] += av[i] * b1.z; acc[i][7] += av[i] * b1.w;
      }
    }
    __syncthreads();
  }

  float4 bias0 = *(const float4*)(tk.bias + tx2 * 8);
  float4 bias1 = *(const float4*)(tk.bias + tx2 * 8 + 4);
  float a_s = 0.f;
  if (EPI_SKIP) a_s = 1.f / (1.f + expf(-tk.skipp[0]));

  #pragma unroll
  for (int i = 0; i < 4; i++) {
    int grow = row0 + ty2 * 4 + i;
    if (grow >= M) continue;
    float o[8];
    o[0] = acc[i][0] + bias0.x; o[1] = acc[i][1] + bias0.y;
    o[2] = acc[i][2] + bias0.z; o[3] = acc[i][3] + bias0.w;
    o[4] = acc[i][4] + bias1.x; o[5] = acc[i][5] + bias1.y;
    o[6] = acc[i][6] + bias1.z; o[7] = acc[i][7] + bias1.w;
    if (RELU) {
      #pragma unroll
      for (int j = 0; j < 8; j++) o[j] = fmaxf(o[j], 0.f);
    }
    if (EPI_SKIP) {
      const float* hp = tk.oldh + (size_t)grow * FDIM + tx2 * 8;
      float4 h0 = *(const float4*)(hp);
      float4 h1 = *(const float4*)(hp + 4);
      float b_s = 1.f - a_s;
      o[0] = a_s * o[0] + b_s * h0.x; o[1] = a_s * o[1] + b_s * h0.y;
      o[2] = a_s * o[2] + b_s * h0.z; o[3] = a_s * o[3] + b_s * h0.w;
      o[4] = a_s * o[4] + b_s * h1.x; o[5] = a_s * o[5] + b_s * h1.y;
      o[6] = a_s * o[6] + b_s * h1.z; o[7] = a_s * o[7] + b_s * h1.w;
    }
    float* cp = tk.C + (size_t)grow * FDIM + tx2 * 8;
    *(float4*)cp = make_float4(o[0], o[1], o[2], o[3]);
    *(float4*)(cp + 4) = make_float4(o[4], o[5], o[6], o[7]);
  }
}

// ------------------------------------------------------- fused rel weights --
// Wf[c, h*16+e] = sum_d W[c, h*16+d] * rel[h, d, e];  bf likewise from bias.
// If scale != nullptr (K path), multiply column (h,e) by scale[h]*0.25
// (folds p_rel * inv_sqrt_d into the fused K weight).
struct FuseBatch { const float* w[8]; const float* b[8]; const float* rel[8]; const float* scale[8]; };

__global__ __launch_bounds__(256) void fuse_w(FuseBatch fb, float* wf, float* bf) {
  const int bx = blockIdx.x;
  const float* w = fb.w[bx];
  const float* bb = fb.b[bx];
  const float* rel = fb.rel[bx];
  const float* scale = fb.scale[bx];
  float* wo = wf + (size_t)bx * FDIM * FDIM;
  float* bo = bf + (size_t)bx * FDIM;
  __shared__ float rl[NH * HD * HD];
  __shared__ float sc[NH];
  for (int i = threadIdx.x; i < NH * HD * HD; i += 256) rl[i] = rel[i];
  if (threadIdx.x < NH) sc[threadIdx.x] = scale ? scale[threadIdx.x] * 0.25f : 1.f;
  __syncthreads();
  for (int idx = threadIdx.x; idx < FDIM * FDIM; idx += 256) {
    int c = idx >> 7, he = idx & 127, h = he >> 4, e2 = he & 15;
    float s = 0.f;
    #pragma unroll
    for (int d2 = 0; d2 < HD; d2++)
      s += w[c * FDIM + h * HD + d2] * rl[h * HD * HD + d2 * HD + e2];
    wo[idx] = s * sc[h];
  }
  if (threadIdx.x < FDIM) {
    int he = threadIdx.x, h = he >> 4, e2 = he & 15;
    float s = 0.f;
    #pragma unroll
    for (int d2 = 0; d2 < HD; d2++)
      s += bb[h * HD + d2] * rl[h * HD * HD + d2 * HD + e2];
    bo[he] = s * sc[h];
  }
}

// ------------------------------------------------------------- CSR build ----
__global__ __launch_bounds__(256) void csr_hist(const int* __restrict__ edge_index,
                                                int* __restrict__ counts) {
  int idx = blockIdx.x * 256 + threadIdx.x;
  if (idx >= NRL * NE_EDGES) return;
  int r = idx / NE_EDGES, e = idx - r * NE_EDGES;
  int d = edge_index[(size_t)(r * 2 + 1) * NE_EDGES + e];
  atomicAdd(&counts[r * NT_NODES + d], 1);
}

// one block (1024 threads) per relation: exclusive scan of counts -> offsets,cursor
__global__ __launch_bounds__(1024) void csr_scan(const int* __restrict__ counts,
                                                 int* __restrict__ offsets,
                                                 int* __restrict__ cursor) {
  const int r = blockIdx.x;
  const int* cnt = counts + r * NT_NODES;
  int* off = offsets + (size_t)r * (NT_NODES + 1);
  int* cur = cursor + r * NT_NODES;
  __shared__ int part[1024];
  const int CH = (NT_NODES + 1023) / 1024;   // 30
  int t = threadIdx.x;
  int lo = t * CH, hi = lo + CH; if (hi > NT_NODES) hi = NT_NODES; if (lo > NT_NODES) lo = NT_NODES;
  int s = 0;
  for (int i = lo; i < hi; i++) s += cnt[i];
  part[t] = s;
  __syncthreads();
  for (int dlt = 1; dlt < 1024; dlt <<= 1) {
    int v = 0;
    if (t >= dlt) v = part[t - dlt];
    __syncthreads();
    if (t >= dlt) part[t] += v;
    __syncthreads();
  }
  int run = (t == 0) ? 0 : part[t - 1];
  for (int i = lo; i < hi; i++) {
    off[i] = run; cur[i] = run;
    run += cnt[i];
  }
  if (t == 1023) off[NT_NODES] = run;
}

__global__ __launch_bounds__(256) void csr_scatter(const int* __restrict__ edge_index,
                                                   int* __restrict__ cursor,
                                                   int* __restrict__ csr_src) {
  int idx = blockIdx.x * 256 + threadIdx.x;
  if (idx >= NRL * NE_EDGES) return;
  int r = idx / NE_EDGES, e = idx - r * NE_EDGES;
  int s = edge_index[(size_t)(r * 2 + 0) * NE_EDGES + e];
  int d = edge_index[(size_t)(r * 2 + 1) * NE_EDGES + e];
  int pos = atomicAdd(&cursor[r * NT_NODES + d], 1);
  csr_src[(size_t)r * NE_EDGES + pos] = s;
}

// ------------------------------------------------------------ attn kernels --
// pass A: thread per (dst,node-head): e=exp(q.k'), store e (CSR order), invsum
__global__ __launch_bounds__(256) void attn_sums(
    const int* __restrict__ csr_src, const int* __restrict__ off,
    const float* __restrict__ q_d, const float* __restrict__ krel,
    float* __restrict__ ebuf, float* __restrict__ invsum) {
  int idx = blockIdx.x * 256 + threadIdx.x;
  if (idx >= NT_NODES * NH) return;
  int d = idx >> 3, h = idx & 7;
  const float4* qp = (const float4*)(q_d + (size_t)d * FDIM + h * HD);
  float4 q0 = qp[0], q1 = qp[1], q2 = qp[2], q3 = qp[3];
  int lo = off[d], hi = off[d + 1];
  float ssum = 0.f;
  for (int pos = lo; pos < hi; pos++) {
    int s = csr_src[pos];
    const float4* kp = (const float4*)(krel + (size_t)s * FDIM + h * HD);
    float4 k0 = kp[0], k1 = kp[1], k2 = kp[2], k3 = kp[3];
    float dot = q0.x * k0.x + q0.y * k0.y + q0.z * k0.z + q0.w * k0.w
              + q1.x * k1.x + q1.y * k1.y + q1.z * k1.z + q1.w * k1.w
              + q2.x * k2.x + q2.y * k2.y + q2.z * k2.z + q2.w * k2.w
              + q3.x * k3.x + q3.y * k3.y + q3.z * k3.z + q3.w * k3.w;
    float e = expf(dot);            // p_rel*0.25 folded into krel weights
    ebuf[(size_t)pos * NH + h] = e;
    ssum += e;
  }
  invsum[idx] = 1.f / (ssum + 1e-16f);
}

// pass B: thread per (dst, 4-channel group): agg[d] += invsum * sum_e e*v'[src]
__global__ __launch_bounds__(256) void attn_agg(
    const int* __restrict__ csr_src, const int* __restrict__ off,
    const float* __restrict__ vrel, const float* __restrict__ ebuf,
    const float* __restrict__ invsum, float* __restrict__ agg) {
  int idx = blockIdx.x * 256 + threadIdx.x;
  if (idx >= NT_NODES * 32) return;
  int d = idx >> 5, c4 = idx & 31, h = c4 >> 2;
  int lo = off[d], hi = off[d + 1];
  float ax = 0.f, ay = 0.f, az = 0.f, aw = 0.f;
  for (int pos = lo; pos < hi; pos++) {
    int s = csr_src[pos];
    float e = ebuf[(size_t)pos * NH + h];
    float4 v = ((const float4*)(vrel + (size_t)s * FDIM))[c4];
    ax += e * v.x; ay += e * v.y; az += e * v.z; aw += e * v.w;
  }
  float inv = invsum[(size_t)d * NH + h];
  float* ap = agg + (size_t)d * FDIM + c4 * 4;
  float4 a = *(float4*)ap;
  a.x += ax * inv; a.y += ay * inv; a.z += az * inv; a.w += aw * inv;
  *(float4*)ap = a;
}

// ---------------------------------------------------------------- scatter ---
__global__ __launch_bounds__(256) void scatter_out(const float* h0, const float* h1,
                                                   const float* h2, const int* ntype,
                                                   float* out, int NN) {
  int idx = blockIdx.x * 256 + threadIdx.x;
  if (idx >= NN * 32) return;
  int i = idx >> 5, c4 = idx & 31;
  int t = ntype[i];
  const float* hp = (t == 0) ? h0 : ((t == 1) ? h1 : h2);
  int local = i - t * NT_NODES;   // node_type_argmax is contiguous blocks per type
  ((float4*)out)[idx] = ((const float4*)hp)[(size_t)local * 32 + c4];
}

// ------------------------------------------------------------------- host ---
static const int ESRC[NRL] = {0, 0, 1, 0};
static const int EDST[NRL] = {0, 1, 0, 2};

extern "C" void kernel_launch(void* const* d_in, const int* in_sizes, int n_in,
                              void* d_out, int out_size, void* d_ws, size_t ws_size,
                              hipStream_t stream) {
  const float* x[3] = {(const float*)d_in[0], (const float*)d_in[1], (const float*)d_in[2]};
  const float* lin_w = (const float*)d_in[4];
  const float* lin_b = (const float*)d_in[5];
  const float* k_w   = (const float*)d_in[6];
  const float* k_b   = (const float*)d_in[7];
  const float* q_w   = (const float*)d_in[8];
  const float* q_b   = (const float*)d_in[9];
  const float* v_w   = (const float*)d_in[10];
  const float* v_b   = (const float*)d_in[11];
  const float* a_w   = (const float*)d_in[12];
  const float* a_b   = (const float*)d_in[13];
  const float* skip  = (const float*)d_in[14];
  const float* a_rel = (const float*)d_in[15];
  const float* m_rel = (const float*)d_in[16];
  const float* p_rel = (const float*)d_in[17];
  const int* edge_index = (const int*)d_in[18];
  const int* ntype   = (const int*)d_in[19];
  float* out = (float*)d_out;

  const size_t NF = (size_t)NT_NODES * FDIM;   // 3.84M floats per [N,128]
  float* p = (float*)d_ws;
  auto alloc = [&](size_t n) { float* r = p; p += n; return r; };
  float* bufA = alloc(3 * NF);                    // h (ping)
  float* bufB = alloc(3 * NF);                    // q-buffer / h (pong)
  float* agg  = alloc(3 * NF);                    // edge aggregation
  float* krel = alloc(NF);                        // per-relation K'
  float* vrel = alloc(NF);                        // per-relation V'
  float* invs = alloc((size_t)NT_NODES * NH);     // per-relation 1/softmax-denom
  float* ebuf = alloc((size_t)NE_EDGES * NH);     // per-relation exp(logit), CSR order
  float* wf   = alloc(8 * (size_t)FDIM * FDIM);   // fused K'/V' weights (8/layer)
  float* bf   = alloc(8 * (size_t)FDIM);
  int* counts  = (int*)(p);                       // 4*N
  int* cursor  = counts + NRL * NT_NODES;         // 4*N
  int* offsets = cursor + NRL * NT_NODES;         // 4*(N+1)
  int* csr_src = offsets + NRL * (NT_NODES + 1);  // 4*E

  const int gemm_gx = (NT_NODES + 63) / 64;   // 469

  // ---- CSR build (edge_index fixed within a call; reused by both layers) ----
  hipMemsetAsync(counts, 0, NRL * NT_NODES * sizeof(int), stream);
  csr_hist<<<dim3((NRL * NE_EDGES + 255) / 256), 256, 0, stream>>>(edge_index, counts);
  csr_scan<<<dim3(NRL), 1024, 0, stream>>>(counts, offsets, cursor);
  csr_scatter<<<dim3((NRL * NE_EDGES + 255) / 256), 256, 0, stream>>>(edge_index, cursor, csr_src);

  // input projection: hs[t] = relu(x_t @ lin_w[t] + lin_b[t])
  {
    GemmBatch gb{};
    for (int t = 0; t < 3; t++) {
      gb.t[t].A = x[t];
      gb.t[t].W = lin_w + (size_t)t * FDIM * FDIM;
      gb.t[t].bias = lin_b + (size_t)t * FDIM;
      gb.t[t].C = bufA + (size_t)t * NF;
      gb.t[t].oldh = nullptr; gb.t[t].skipp = nullptr;
    }
    gemm_f32<0, 0, 1><<<dim3(gemm_gx, 1, 3), 256, 0, stream>>>(gb, NT_NODES);
  }

  float* cur = bufA;   // current h
  float* alt = bufB;   // q-buffer, then next h
  for (int l = 0; l < NLY; l++) {
    // fused K/V relation weights (8 tiny problems in one launch)
    {
      FuseBatch fb{};
      for (int r = 0; r < NRL; r++) {
        int s = ESRC[r];
        fb.w[2 * r]     = k_w + (size_t)(l * NTY + s) * FDIM * FDIM;
        fb.b[2 * r]     = k_b + (size_t)(l * NTY + s) * FDIM;
        fb.rel[2 * r]   = a_rel + (size_t)(l * NRL + r) * NH * HD * HD;
        fb.scale[2 * r] = p_rel + (size_t)(l * NRL + r) * NH;   // fold p_rel/4 into K'
        fb.w[2 * r + 1]   = v_w + (size_t)(l * NTY + s) * FDIM * FDIM;
        fb.b[2 * r + 1]   = v_b + (size_t)(l * NTY + s) * FDIM;
        fb.rel[2 * r + 1] = m_rel + (size_t)(l * NRL + r) * NH * HD * HD;
        fb.scale[2 * r + 1] = nullptr;
      }
      fuse_w<<<dim3(8), 256, 0, stream>>>(fb, wf, bf);
    }
    hipMemsetAsync(agg, 0, 3 * NF * sizeof(float), stream);

    // q projections for all 3 types (into alt)
    {
      GemmBatch gb{};
      for (int t = 0; t < 3; t++) {
        gb.t[t].A = cur + (size_t)t * NF;
        gb.t[t].W = q_w + (size_t)(l * NTY + t) * FDIM * FDIM;
        gb.t[t].bias = q_b + (size_t)(l * NTY + t) * FDIM;
        gb.t[t].C = alt + (size_t)t * NF;
        gb.t[t].oldh = nullptr; gb.t[t].skipp = nullptr;
      }
      gemm_f32<0, 0, 0><<<dim3(gemm_gx, 1, 3), 256, 0, stream>>>(gb, NT_NODES);
    }

    // relations, sequential (krel/vrel/ebuf/invs reused)
    for (int r = 0; r < NRL; r++) {
      int s = ESRC[r], d = EDST[r];
      {
        GemmBatch gb{};
        gb.t[0].A = cur + (size_t)s * NF;
        gb.t[0].W = wf + (size_t)(2 * r) * FDIM * FDIM;
        gb.t[0].bias = bf + (size_t)(2 * r) * FDIM;
        gb.t[0].C = krel;
        gb.t[0].oldh = nullptr; gb.t[0].skipp = nullptr;
        gb.t[1].A = cur + (size_t)s * NF;
        gb.t[1].W = wf + (size_t)(2 * r + 1) * FDIM * FDIM;
        gb.t[1].bias = bf + (size_t)(2 * r + 1) * FDIM;
        gb.t[1].C = vrel;
        gb.t[1].oldh = nullptr; gb.t[1].skipp = nullptr;
        gemm_f32<0, 0, 0><<<dim3(gemm_gx, 1, 2), 256, 0, stream>>>(gb, NT_NODES);
      }
      const int* offp = offsets + (size_t)r * (NT_NODES + 1);
      const int* srcp = csr_src + (size_t)r * NE_EDGES;
      attn_sums<<<dim3((NT_NODES * NH + 255) / 256), 256, 0, stream>>>(
          srcp, offp, alt + (size_t)d * NF, krel, ebuf, invs);
      attn_agg<<<dim3((NT_NODES * 32 + 255) / 256), 256, 0, stream>>>(
          srcp, offp, vrel, ebuf, invs, agg + (size_t)d * NF);
    }

    // out: hs_new[t] = a_s*(gelu(agg[t]) @ a_w + a_b) + (1-a_s)*hs[t]
    // writes over the q-buffer (q is dead now)
    {
      GemmBatch gb{};
      for (int t = 0; t < 3; t++) {
        gb.t[t].A = agg + (size_t)t * NF;
        gb.t[t].W = a_w + (size_t)(l * NTY + t) * FDIM * FDIM;
        gb.t[t].bias = a_b + (size_t)(l * NTY + t) * FDIM;
        gb.t[t].C = alt + (size_t)t * NF;
        gb.t[t].oldh = cur + (size_t)t * NF;
        gb.t[t].skipp = skip + (size_t)(l * NTY + t);
      }
      gemm_f32<1, 1, 0><<<dim3(gemm_gx, 1, 3), 256, 0, stream>>>(gb, NT_NODES);
    }
    float* tmp = cur; cur = alt; alt = tmp;
  }

  // scatter per-type rows back to global node order
  const int NN = 3 * NT_NODES;
  scatter_out<<<dim3((NN * 32 + 255) / 256), 256, 0, stream>>>(
      cur, cur + NF, cur + 2 * NF, ntype, out, NN);
}

// Round 4
// 862.009 us; speedup vs baseline: 4.1271x; 1.2642x over previous
//
#include <hip/hip_runtime.h>
#include <math.h>

#define NT_NODES 30000
#define NE_EDGES 200000
#define NTY 3
#define NRL 4
#define NLY 2
#define NH 8
#define HD 16
#define FDIM 128
#define SCAN_BLOCKS 118   // ceil(30000/256)

// ---------------------------------------------------------------- GEMM ------
struct GemmTask {
  const float* A; const float* W; const float* bias; float* C;
  const float* oldh; const float* skipp;
};
struct GemmBatch { GemmTask t[7]; };

__device__ __forceinline__ float gelu_f(float x) {
  return 0.5f * x * (1.f + erff(x * 0.7071067811865475f));
}

// C[M,128] = epi(preA(A)[M,128] @ W[128,128] + bias)
template<int GELU_A, int EPI_SKIP, int RELU>
__global__ __launch_bounds__(256) void gemm_f32(GemmBatch gb, int M) {
  const GemmTask tk = gb.t[blockIdx.z];
  const int tid = threadIdx.x;
  const int tx2 = tid & 15;    // col group of 8
  const int ty2 = tid >> 4;    // row group of 4
  const int row0 = blockIdx.x * 64;

  __shared__ float AsT[32][64];   // transposed A chunk [k][row]
  __shared__ float Bs[32][128];   // B chunk [k][col]

  float acc[4][8];
  #pragma unroll
  for (int i = 0; i < 4; i++)
    #pragma unroll
    for (int j = 0; j < 8; j++) acc[i][j] = 0.f;

  for (int k0 = 0; k0 < FDIM; k0 += 32) {
    #pragma unroll
    for (int i = 0; i < 2; i++) {
      int slot = tid + 256 * i;         // 0..511
      int r = slot >> 3, f4 = slot & 7;
      int grow = row0 + r;
      float4 v = make_float4(0.f, 0.f, 0.f, 0.f);
      if (grow < M) v = *(const float4*)(tk.A + (size_t)grow * FDIM + k0 + f4 * 4);
      if (GELU_A) { v.x = gelu_f(v.x); v.y = gelu_f(v.y); v.z = gelu_f(v.z); v.w = gelu_f(v.w); }
      AsT[f4 * 4 + 0][r] = v.x;
      AsT[f4 * 4 + 1][r] = v.y;
      AsT[f4 * 4 + 2][r] = v.z;
      AsT[f4 * 4 + 3][r] = v.w;
    }
    #pragma unroll
    for (int i = 0; i < 4; i++) {
      int slot = tid + 256 * i;         // 0..1023
      int r = slot >> 5, f4 = slot & 31;
      float4 v = *(const float4*)(tk.W + (size_t)(k0 + r) * FDIM + f4 * 4);
      *(float4*)(&Bs[r][f4 * 4]) = v;
    }
    __syncthreads();
    #pragma unroll
    for (int kk = 0; kk < 32; kk++) {
      float4 a4 = *(const float4*)(&AsT[kk][ty2 * 4]);
      float4 b0 = *(const float4*)(&Bs[kk][tx2 * 8]);
      float4 b1 = *(const float4*)(&Bs[kk][tx2 * 8 + 4]);
      const float av[4] = {a4.x, a4.y, a4.z, a4.w};
      #pragma unroll
      for (int i = 0; i < 4; i++) {
        acc[i][0] += av[i] * b0.x; acc[i][1] += av[i] * b0.y;
        acc[i][2] += av[i] * b0.z; acc[i][3] += av[i] * b0.w;
        acc[i][4] += av[i] * b1.x; acc[i][5] += av[i] * b1.y;
        acc[i][6] += av[i] * b1.z; acc[i][7] += av[i] * b1.w;
      }
    }
    __syncthreads();
  }

  float4 bias0 = *(const float4*)(tk.bias + tx2 * 8);
  float4 bias1 = *(const float4*)(tk.bias + tx2 * 8 + 4);
  float a_s = 0.f;
  if (EPI_SKIP) a_s = 1.f / (1.f + expf(-tk.skipp[0]));

  #pragma unroll
  for (int i = 0; i < 4; i++) {
    int grow = row0 + ty2 * 4 + i;
    if (grow >= M) continue;
    float o[8];
    o[0] = acc[i][0] + bias0.x; o[1] = acc[i][1] + bias0.y;
    o[2] = acc[i][2] + bias0.z; o[3] = acc[i][3] + bias0.w;
    o[4] = acc[i][4] + bias1.x; o[5] = acc[i][5] + bias1.y;
    o[6] = acc[i][6] + bias1.z; o[7] = acc[i][7] + bias1.w;
    if (RELU) {
      #pragma unroll
      for (int j = 0; j < 8; j++) o[j] = fmaxf(o[j], 0.f);
    }
    if (EPI_SKIP) {
      const float* hp = tk.oldh + (size_t)grow * FDIM + tx2 * 8;
      float4 h0 = *(const float4*)(hp);
      float4 h1 = *(const float4*)(hp + 4);
      float b_s = 1.f - a_s;
      o[0] = a_s * o[0] + b_s * h0.x; o[1] = a_s * o[1] + b_s * h0.y;
      o[2] = a_s * o[2] + b_s * h0.z; o[3] = a_s * o[3] + b_s * h0.w;
      o[4] = a_s * o[4] + b_s * h1.x; o[5] = a_s * o[5] + b_s * h1.y;
      o[6] = a_s * o[6] + b_s * h1.z; o[7] = a_s * o[7] + b_s * h1.w;
    }
    float* cp = tk.C + (size_t)grow * FDIM + tx2 * 8;
    *(float4*)cp = make_float4(o[0], o[1], o[2], o[3]);
    *(float4*)(cp + 4) = make_float4(o[4], o[5], o[6], o[7]);
  }
}

// ------------------------------------------------------------- CSR build ----
__global__ __launch_bounds__(256) void csr_hist(const int* __restrict__ edge_index,
                                                int* __restrict__ counts) {
  int idx = blockIdx.x * 256 + threadIdx.x;
  if (idx >= NRL * NE_EDGES) return;
  int r = idx / NE_EDGES, e = idx - r * NE_EDGES;
  int d = edge_index[(size_t)(r * 2 + 1) * NE_EDGES + e];
  atomicAdd(&counts[r * NT_NODES + d], 1);
}

// hierarchical scan: block-local -> aux -> add-back
__global__ __launch_bounds__(256) void scan_block(const int* __restrict__ counts,
                                                  int* __restrict__ off,
                                                  int* __restrict__ aux) {
  int r = blockIdx.y, b = blockIdx.x, t = threadIdx.x;
  int i = b * 256 + t;
  int v = (i < NT_NODES) ? counts[r * NT_NODES + i] : 0;
  __shared__ int lds[256];
  lds[t] = v;
  __syncthreads();
  #pragma unroll
  for (int dlt = 1; dlt < 256; dlt <<= 1) {
    int x = (t >= dlt) ? lds[t - dlt] : 0;
    __syncthreads();
    lds[t] += x;
    __syncthreads();
  }
  if (i < NT_NODES) off[(size_t)r * (NT_NODES + 1) + i] = lds[t] - v;  // block-local exclusive
  if (t == 255) aux[r * SCAN_BLOCKS + b] = lds[255];
}

__global__ __launch_bounds__(128) void scan_aux(const int* __restrict__ aux,
                                                int* __restrict__ auxe,
                                                int* __restrict__ off) {
  int r = blockIdx.x, t = threadIdx.x;
  __shared__ int lds[128];
  int v = (t < SCAN_BLOCKS) ? aux[r * SCAN_BLOCKS + t] : 0;
  lds[t] = v;
  __syncthreads();
  #pragma unroll
  for (int dlt = 1; dlt < 128; dlt <<= 1) {
    int x = (t >= dlt) ? lds[t - dlt] : 0;
    __syncthreads();
    lds[t] += x;
    __syncthreads();
  }
  if (t < SCAN_BLOCKS) auxe[r * SCAN_BLOCKS + t] = lds[t] - v;   // exclusive
  if (t == 127) off[(size_t)r * (NT_NODES + 1) + NT_NODES] = lds[127];  // grand total
}

__global__ __launch_bounds__(256) void scan_add(const int* __restrict__ auxe,
                                                int* __restrict__ off,
                                                int* __restrict__ cursor) {
  int r = blockIdx.y, b = blockIdx.x, t = threadIdx.x;
  int i = b * 256 + t;
  if (i >= NT_NODES) return;
  int val = off[(size_t)r * (NT_NODES + 1) + i] + auxe[r * SCAN_BLOCKS + b];
  off[(size_t)r * (NT_NODES + 1) + i] = val;
  cursor[r * NT_NODES + i] = val;
}

__global__ __launch_bounds__(256) void csr_scatter(const int* __restrict__ edge_index,
                                                   int* __restrict__ cursor,
                                                   int* __restrict__ csr_src) {
  int idx = blockIdx.x * 256 + threadIdx.x;
  if (idx >= NRL * NE_EDGES) return;
  int r = idx / NE_EDGES, e = idx - r * NE_EDGES;
  int s = edge_index[(size_t)(r * 2 + 0) * NE_EDGES + e];
  int d = edge_index[(size_t)(r * 2 + 1) * NE_EDGES + e];
  int pos = atomicAdd(&cursor[r * NT_NODES + d], 1);
  csr_src[(size_t)r * NE_EDGES + pos] = s;
}

// ---------------------------------------------------- fused attention -------
// One wave (64 lanes) per dst node per relation. Lane owns channels {l, 64+l}.
// q' = (A_rel @ q) * p/4 in-register (shfl within 16-lane head groups);
// online softmax-free accumulation of (sum e*v_raw, sum e); epilogue applies
// M_rel per head and accumulates into agg[d] (unique wave per row -> no atomics).
struct AttnRel {
  const int* csr_src; const int* off;
  const float* q;      // raw Q of dst type [N,128]
  const float* kraw;   // raw K of src type [N,128]
  const float* vraw;   // raw V of src type [N,128]
  const float* Arel;   // a_rel[l][r]: [8][16][16]
  const float* Mrel;   // m_rel[l][r]: [8][16][16]
  const float* prel;   // p_rel[l][r]: [8]
  float* agg;          // agg of dst type [N,128]
};
struct AttnBatch { AttnRel r[3]; };

__global__ __launch_bounds__(256) void attn_fused(AttnBatch ab) {
  const AttnRel rp = ab.r[blockIdx.y];
  const int wave = threadIdx.x >> 6;
  const int lane = threadIdx.x & 63;
  const int d = blockIdx.x * 4 + wave;
  if (d >= NT_NODES) return;
  const int h0 = lane >> 4;        // head of channel c0=lane (0..3); c1 head = h0+4
  const int e0 = lane & 15;        // within-head index
  const int grpbase = h0 << 4;

  // ---- load q row, compute q' = (A_h @ q_h) * p_h/4 via shfl ----
  float ql0 = rp.q[(size_t)d * FDIM + lane];
  float ql1 = rp.q[(size_t)d * FDIM + 64 + lane];
  const float* A0 = rp.Arel + (size_t)h0 * 256 + e0 * 16;         // A[h0][e0][*]
  const float* A1 = rp.Arel + (size_t)(h0 + 4) * 256 + e0 * 16;
  float qp0 = 0.f, qp1 = 0.f;
  #pragma unroll
  for (int e = 0; e < 16; e++) {
    float qe0 = __shfl(ql0, grpbase + e, 64);
    float qe1 = __shfl(ql1, grpbase + e, 64);
    qp0 += A0[e] * qe0;
    qp1 += A1[e] * qe1;
  }
  qp0 *= rp.prel[h0] * 0.25f;
  qp1 *= rp.prel[h0 + 4] * 0.25f;

  // ---- edge loop: online accumulation in raw-V space ----
  int lo = rp.off[d], hi = rp.off[d + 1];
  float acc0 = 0.f, acc1 = 0.f, ssum0 = 0.f, ssum1 = 0.f;
  for (int pos = lo; pos < hi; pos++) {
    int s = rp.csr_src[pos];
    size_t base = (size_t)s * FDIM;
    float p0 = qp0 * rp.kraw[base + lane];
    float p1 = qp1 * rp.kraw[base + 64 + lane];
    #pragma unroll
    for (int m = 1; m < 16; m <<= 1) {
      p0 += __shfl_xor(p0, m, 64);
      p1 += __shfl_xor(p1, m, 64);
    }
    float ev0 = expf(p0), ev1 = expf(p1);
    float vv0 = rp.vraw[base + lane];
    float vv1 = rp.vraw[base + 64 + lane];
    acc0 += ev0 * vv0; acc1 += ev1 * vv1;
    ssum0 += ev0; ssum1 += ev1;
  }
  float S0 = acc0 / (ssum0 + 1e-16f);
  float S1 = acc1 / (ssum1 + 1e-16f);

  // ---- apply M_rel per head: out_c = sum_d2 S[h,d2] * M[h][d2][e0] ----
  const float* M0 = rp.Mrel + (size_t)h0 * 256;
  const float* M1 = rp.Mrel + (size_t)(h0 + 4) * 256;
  float o0 = 0.f, o1 = 0.f;
  #pragma unroll
  for (int d2 = 0; d2 < 16; d2++) {
    float s0 = __shfl(S0, grpbase + d2, 64);
    float s1 = __shfl(S1, grpbase + d2, 64);
    o0 += s0 * M0[d2 * 16 + e0];
    o1 += s1 * M1[d2 * 16 + e0];
  }
  float* ap = rp.agg + (size_t)d * FDIM;
  ap[lane] += o0;
  ap[64 + lane] += o1;
}

// ---------------------------------------------------------------- scatter ---
__global__ __launch_bounds__(256) void scatter_out(const float* h0, const float* h1,
                                                   const float* h2, const int* ntype,
                                                   float* out, int NN) {
  int idx = blockIdx.x * 256 + threadIdx.x;
  if (idx >= NN * 32) return;
  int i = idx >> 5, c4 = idx & 31;
  int t = ntype[i];
  const float* hp = (t == 0) ? h0 : ((t == 1) ? h1 : h2);
  int local = i - t * NT_NODES;   // node_type_argmax is contiguous blocks per type
  ((float4*)out)[idx] = ((const float4*)hp)[(size_t)local * 32 + c4];
}

// ------------------------------------------------------------------- host ---
static const int ESRC[NRL] = {0, 0, 1, 0};
static const int EDST[NRL] = {0, 1, 0, 2};

extern "C" void kernel_launch(void* const* d_in, const int* in_sizes, int n_in,
                              void* d_out, int out_size, void* d_ws, size_t ws_size,
                              hipStream_t stream) {
  const float* x[3] = {(const float*)d_in[0], (const float*)d_in[1], (const float*)d_in[2]};
  const float* lin_w = (const float*)d_in[4];
  const float* lin_b = (const float*)d_in[5];
  const float* k_w   = (const float*)d_in[6];
  const float* k_b   = (const float*)d_in[7];
  const float* q_w   = (const float*)d_in[8];
  const float* q_b   = (const float*)d_in[9];
  const float* v_w   = (const float*)d_in[10];
  const float* v_b   = (const float*)d_in[11];
  const float* a_w   = (const float*)d_in[12];
  const float* a_b   = (const float*)d_in[13];
  const float* skip  = (const float*)d_in[14];
  const float* a_rel = (const float*)d_in[15];
  const float* m_rel = (const float*)d_in[16];
  const float* p_rel = (const float*)d_in[17];
  const int* edge_index = (const int*)d_in[18];
  const int* ntype   = (const int*)d_in[19];
  float* out = (float*)d_out;

  const size_t NF = (size_t)NT_NODES * FDIM;   // 3.84M floats per [N,128]
  float* p = (float*)d_ws;
  auto alloc = [&](size_t n) { float* r = p; p += n; return r; };
  float* bufA = alloc(3 * NF);                    // h (ping)
  float* bufB = alloc(3 * NF);                    // q-buffer / h (pong)
  float* agg  = alloc(3 * NF);                    // edge aggregation (raw-V then M'd)
  float* kraw = alloc(NF);                        // raw K of current src type
  float* vraw = alloc(NF);                        // raw V of current src type
  int* counts  = (int*)(p);                       // [4][N]
  int* cursor  = counts + NRL * NT_NODES;         // [4][N]
  int* offsets = cursor + NRL * NT_NODES;         // [4][N+1]
  int* aux     = offsets + NRL * (NT_NODES + 1);  // [4][118]
  int* auxe    = aux + NRL * SCAN_BLOCKS;         // [4][118]
  int* csr_src = auxe + NRL * SCAN_BLOCKS;        // [4][E]

  const int gemm_gx = (NT_NODES + 63) / 64;   // 469

  // ---- CSR build (edge_index fixed within a call; reused by both layers) ----
  hipMemsetAsync(counts, 0, NRL * NT_NODES * sizeof(int), stream);
  csr_hist<<<dim3((NRL * NE_EDGES + 255) / 256), 256, 0, stream>>>(edge_index, counts);
  scan_block<<<dim3(SCAN_BLOCKS, NRL), 256, 0, stream>>>(counts, offsets, aux);
  scan_aux<<<dim3(NRL), 128, 0, stream>>>(aux, auxe, offsets);
  scan_add<<<dim3(SCAN_BLOCKS, NRL), 256, 0, stream>>>(auxe, offsets, cursor);
  csr_scatter<<<dim3((NRL * NE_EDGES + 255) / 256), 256, 0, stream>>>(edge_index, cursor, csr_src);

  // input projection: hs[t] = relu(x_t @ lin_w[t] + lin_b[t])
  {
    GemmBatch gb{};
    for (int t = 0; t < 3; t++) {
      gb.t[t].A = x[t];
      gb.t[t].W = lin_w + (size_t)t * FDIM * FDIM;
      gb.t[t].bias = lin_b + (size_t)t * FDIM;
      gb.t[t].C = bufA + (size_t)t * NF;
    }
    gemm_f32<0, 0, 1><<<dim3(gemm_gx, 1, 3), 256, 0, stream>>>(gb, NT_NODES);
  }

  float* cur = bufA;   // current h
  float* alt = bufB;   // q-buffer, then next h
  for (int l = 0; l < NLY; l++) {
    hipMemsetAsync(agg, 0, 3 * NF * sizeof(float), stream);

    // Q for all 3 types + raw K/V for src type 0 (relations 0,1,3): one launch
    {
      GemmBatch gb{};
      for (int t = 0; t < 3; t++) {
        gb.t[t].A = cur + (size_t)t * NF;
        gb.t[t].W = q_w + (size_t)(l * NTY + t) * FDIM * FDIM;
        gb.t[t].bias = q_b + (size_t)(l * NTY + t) * FDIM;
        gb.t[t].C = alt + (size_t)t * NF;
      }
      gb.t[3].A = cur;                                   // src type 0
      gb.t[3].W = k_w + (size_t)(l * NTY + 0) * FDIM * FDIM;
      gb.t[3].bias = k_b + (size_t)(l * NTY + 0) * FDIM;
      gb.t[3].C = kraw;
      gb.t[4].A = cur;
      gb.t[4].W = v_w + (size_t)(l * NTY + 0) * FDIM * FDIM;
      gb.t[4].bias = v_b + (size_t)(l * NTY + 0) * FDIM;
      gb.t[4].C = vraw;
      gemm_f32<0, 0, 0><<<dim3(gemm_gx, 1, 5), 256, 0, stream>>>(gb, NT_NODES);
    }

    // attention launch A: relations {0,1,3} (src type 0; dst types 0,1,2 disjoint)
    {
      AttnBatch ab{};
      const int rels[3] = {0, 1, 3};
      for (int j = 0; j < 3; j++) {
        int r = rels[j], dt = EDST[r];
        ab.r[j].csr_src = csr_src + (size_t)r * NE_EDGES;
        ab.r[j].off  = offsets + (size_t)r * (NT_NODES + 1);
        ab.r[j].q    = alt + (size_t)dt * NF;
        ab.r[j].kraw = kraw;
        ab.r[j].vraw = vraw;
        ab.r[j].Arel = a_rel + (size_t)(l * NRL + r) * NH * HD * HD;
        ab.r[j].Mrel = m_rel + (size_t)(l * NRL + r) * NH * HD * HD;
        ab.r[j].prel = p_rel + (size_t)(l * NRL + r) * NH;
        ab.r[j].agg  = agg + (size_t)dt * NF;
      }
      attn_fused<<<dim3((NT_NODES + 3) / 4, 3), 256, 0, stream>>>(ab);
    }

    // raw K/V for src type 1 (relation 2), reusing the buffers
    {
      GemmBatch gb{};
      gb.t[0].A = cur + NF;                              // src type 1
      gb.t[0].W = k_w + (size_t)(l * NTY + 1) * FDIM * FDIM;
      gb.t[0].bias = k_b + (size_t)(l * NTY + 1) * FDIM;
      gb.t[0].C = kraw;
      gb.t[1].A = cur + NF;
      gb.t[1].W = v_w + (size_t)(l * NTY + 1) * FDIM * FDIM;
      gb.t[1].bias = v_b + (size_t)(l * NTY + 1) * FDIM;
      gb.t[1].C = vraw;
      gemm_f32<0, 0, 0><<<dim3(gemm_gx, 1, 2), 256, 0, stream>>>(gb, NT_NODES);
    }

    // attention launch B: relation {2} (src type 1, dst type 0)
    {
      AttnBatch ab{};
      int r = 2, dt = EDST[r];
      ab.r[0].csr_src = csr_src + (size_t)r * NE_EDGES;
      ab.r[0].off  = offsets + (size_t)r * (NT_NODES + 1);
      ab.r[0].q    = alt + (size_t)dt * NF;
      ab.r[0].kraw = kraw;
      ab.r[0].vraw = vraw;
      ab.r[0].Arel = a_rel + (size_t)(l * NRL + r) * NH * HD * HD;
      ab.r[0].Mrel = m_rel + (size_t)(l * NRL + r) * NH * HD * HD;
      ab.r[0].prel = p_rel + (size_t)(l * NRL + r) * NH;
      ab.r[0].agg  = agg + (size_t)dt * NF;
      attn_fused<<<dim3((NT_NODES + 3) / 4, 1), 256, 0, stream>>>(ab);
    }

    // out: hs_new[t] = a_s*(gelu(agg[t]) @ a_w + a_b) + (1-a_s)*hs[t]
    {
      GemmBatch gb{};
      for (int t = 0; t < 3; t++) {
        gb.t[t].A = agg + (size_t)t * NF;
        gb.t[t].W = a_w + (size_t)(l * NTY + t) * FDIM * FDIM;
        gb.t[t].bias = a_b + (size_t)(l * NTY + t) * FDIM;
        gb.t[t].C = alt + (size_t)t * NF;
        gb.t[t].oldh = cur + (size_t)t * NF;
        gb.t[t].skipp = skip + (size_t)(l * NTY + t);
      }
      gemm_f32<1, 1, 0><<<dim3(gemm_gx, 1, 3), 256, 0, stream>>>(gb, NT_NODES);
    }
    float* tmp = cur; cur = alt; alt = tmp;
  }

  // scatter per-type rows back to global node order
  const int NN = 3 * NT_NODES;
  scatter_out<<<dim3((NN * 32 + 255) / 256), 256, 0, stream>>>(
      cur, cur + NF, cur + 2 * NF, ntype, out, NN);
}